// Round 2
// baseline (336.498 us; speedup 1.0000x reference)
//
#include <hip/hip_runtime.h>
#include <hip/hip_bf16.h>

// ---------------------------------------------------------------------------
// QuixerCore: 10-qubit QSVT/LCU quantum circuit simulator.
// State layout per wave: n = r*64 + lane  (lane bits = n[0:5], reg bits = n[6:9])
// Qubit (wire) w lives at bit p = 9 - w of n.
//   wires 4..9 -> lane bits p=5..0 ; wires 0..3 -> register bits p=9..6
// R2: no global atomics. Step kernel = 512 blocks x 512 thr; block = (b, quarter),
// 8 waves = 8 tokens, LDS-atomic reduce -> 1 partial per block; next stage sums
// the 4 partials on load.
// ---------------------------------------------------------------------------

#define NQ   10
#define NT   32
#define DM   512
#define BATCH 128
#define NPQC 40
#define DIM  1024
#define NROWS (BATCH * NT)   // 4096
#define PSTRIDE (BATCH * DIM) // elements per partial slice (float2)

// ------------------------- gate primitives (per-wave) ----------------------

template<int PT>
__device__ __forceinline__ void g_ry(float (&ar)[16], float (&ai)[16], int lane,
                                     float c, float s) {
  if constexpr (PT >= 6) {
    constexpr int m = 1 << (PT - 6);
#pragma unroll
    for (int r = 0; r < 16; ++r) {
      if (!(r & m)) {
        int r1 = r | m;
        float a0r = ar[r], a0i = ai[r], a1r = ar[r1], a1i = ai[r1];
        ar[r]  = c * a0r - s * a1r;  ai[r]  = c * a0i - s * a1i;
        ar[r1] = s * a0r + c * a1r;  ai[r1] = s * a0i + c * a1i;
      }
    }
  } else {
    constexpr int lm = 1 << PT;
    float se = (lane & lm) ? s : -s;
#pragma unroll
    for (int r = 0; r < 16; ++r) {
      float pr = __shfl_xor(ar[r], lm);
      float pi = __shfl_xor(ai[r], lm);
      ar[r] = c * ar[r] + se * pr;
      ai[r] = c * ai[r] + se * pi;
    }
  }
}

template<int PC, int PT>
__device__ __forceinline__ void g_crx(float (&ar)[16], float (&ai)[16], int lane,
                                      float c, float s) {
  if constexpr (PT >= 6) {
    constexpr int m = 1 << (PT - 6);
    bool lane_ok = (PC >= 6) || ((lane >> PC) & 1);
#pragma unroll
    for (int r = 0; r < 16; ++r) {
      if (!(r & m)) {
        if constexpr (PC >= 6) { if (!((r >> (PC - 6)) & 1)) continue; }
        int r1 = r | m;
        float a0r = ar[r], a0i = ai[r], a1r = ar[r1], a1i = ai[r1];
        float n0r = c * a0r + s * a1i, n0i = c * a0i - s * a1r;
        float n1r = c * a1r + s * a0i, n1i = c * a1i - s * a0r;
        if (lane_ok) { ar[r] = n0r; ai[r] = n0i; ar[r1] = n1r; ai[r1] = n1i; }
      }
    }
  } else {
    constexpr int lm = 1 << PT;
    bool lane_ok = (PC >= 6) || ((lane >> PC) & 1);
#pragma unroll
    for (int r = 0; r < 16; ++r) {
      bool act = lane_ok;
      if constexpr (PC >= 6) act = act && ((r >> (PC - 6)) & 1);
      float pr = __shfl_xor(ar[r], lm);
      float pi = __shfl_xor(ai[r], lm);
      float nr = c * ar[r] + s * pi;
      float ni = c * ai[r] - s * pr;
      if (act) { ar[r] = nr; ai[r] = ni; }
    }
  }
}

__device__ __forceinline__ void apply_pqc(float (&ar)[16], float (&ai)[16],
                                          const float2* __restrict__ cs, int lane) {
  float2 t;
#define RYG(k, PT)     t = cs[k]; g_ry<PT>(ar, ai, lane, t.x, t.y);
#define CXG(k, PC, PT) t = cs[k]; g_crx<PC, PT>(ar, ai, lane, t.x, t.y);
  RYG(0,9) RYG(1,8) RYG(2,7) RYG(3,6) RYG(4,5)
  RYG(5,4) RYG(6,3) RYG(7,2) RYG(8,1) RYG(9,0)
  CXG(10,0,9) CXG(11,1,0) CXG(12,2,1) CXG(13,3,2) CXG(14,4,3)
  CXG(15,5,4) CXG(16,6,5) CXG(17,7,6) CXG(18,8,7) CXG(19,9,8)
  RYG(20,9) RYG(21,8) RYG(22,7) RYG(23,6) RYG(24,5)
  RYG(25,4) RYG(26,3) RYG(27,2) RYG(28,1) RYG(29,0)
  CXG(30,0,1) CXG(31,9,0) CXG(32,8,9) CXG(33,7,8) CXG(34,6,7)
  CXG(35,5,6) CXG(36,4,5) CXG(37,3,4) CXG(38,2,3) CXG(39,1,2)
#undef RYG
#undef CXG
}

// ------------------------- kernels -----------------------------------------

__global__ __launch_bounds__(320) void params_kernel(
    const float* __restrict__ emb, const float* __restrict__ W,
    const float* __restrict__ bias,
    const float* __restrict__ lcu_re, const float* __restrict__ lcu_im,
    const float* __restrict__ ffp,
    float2* __restrict__ cs, float2* __restrict__ ffcs, float2* __restrict__ lcu) {
  int row = blockIdx.x;
  int t = threadIdx.x;
  if (row == NROWS) {
    if (t < NPQC) {
      float h = 0.5f * ffp[t];
      ffcs[t] = make_float2(cosf(h), sinf(h));
    }
    if (t == 64) {
      float ssum = 0.f;
      for (int i = 0; i < NT; ++i) {
        float re = lcu_re[i], im = lcu_im[i];
        ssum += sqrtf(re * re + im * im);
      }
      float inv = 1.f / ssum;
      for (int i = 0; i < NT; ++i)
        lcu[i] = make_float2(lcu_re[i] * inv, lcu_im[i] * inv);
    }
    return;
  }
  __shared__ float partials[NPQC][8];
  int k = t >> 3, part = t & 7;
  const float4* e4 = (const float4*)(emb + (size_t)row * DM + part * 64);
  const float4* w4 = (const float4*)(W + (size_t)k * DM + part * 64);
  float acc = 0.f;
#pragma unroll
  for (int i = 0; i < 16; ++i) {
    float4 a = e4[i], b = w4[i];
    acc += a.x * b.x + a.y * b.y + a.z * b.z + a.w * b.w;
  }
  partials[k][part] = acc;
  __syncthreads();
  if (t < NPQC) {
    float v = bias[t];
#pragma unroll
    for (int p = 0; p < 8; ++p) v += partials[t][p];
    float h = 0.5f * v;
    cs[(size_t)row * NPQC + t] = make_float2(cosf(h), sinf(h));
  }
}

// One QSVT step without global atomics.
// grid = 512 blocks (b = blk>>2, quarter q = blk&3), block = 512 thr = 8 waves,
// wave wv handles token l = q*8+wv. LDS-atomic reduce, write one partial slice.
// FIRST: src state = e0. Else: src state = sum of 4 partials at `src`.
template<bool FIRST>
__global__ __launch_bounds__(512) void pqc_step(
    const float2* __restrict__ cs, const float2* __restrict__ lcu,
    const float2* __restrict__ src, float2* __restrict__ dst) {
  int blk = blockIdx.x;
  int b = blk >> 2, qq = blk & 3;
  int wv = threadIdx.x >> 6;
  int lane = threadIdx.x & 63;
  int l = qq * 8 + wv;
  const float2* csrow = cs + (size_t)(b * NT + l) * NPQC;

  __shared__ float red[2 * DIM];
#pragma unroll
  for (int i = 0; i < 4; ++i) red[threadIdx.x + i * 512] = 0.f;
  __syncthreads();

  float ar[16], ai[16];
  if constexpr (FIRST) {
#pragma unroll
    for (int r = 0; r < 16; ++r) { ar[r] = 0.f; ai[r] = 0.f; }
    if (lane == 0) ar[0] = 1.f;   // |0...0>
  } else {
    const float2* s = src + (size_t)b * DIM;
#pragma unroll
    for (int r = 0; r < 16; ++r) {
      int n = r * 64 + lane;
      float2 v0 = s[n];
      float2 v1 = s[n + PSTRIDE];
      float2 v2 = s[n + 2 * PSTRIDE];
      float2 v3 = s[n + 3 * PSTRIDE];
      ar[r] = v0.x + v1.x + v2.x + v3.x;
      ai[r] = v0.y + v1.y + v2.y + v3.y;
    }
  }

  apply_pqc(ar, ai, csrow, lane);

  float2 w = lcu[l];
#pragma unroll
  for (int r = 0; r < 16; ++r) {
    float cr = w.x * ar[r] - w.y * ai[r];
    float ci = w.x * ai[r] + w.y * ar[r];
    int n = r * 64 + lane;
    atomicAdd(&red[2 * n + 0], cr);
    atomicAdd(&red[2 * n + 1], ci);
  }
  __syncthreads();

  // write this block's partial slice (8 KB coalesced)
  float4* out4 = (float4*)(dst + (size_t)(qq * BATCH + b) * DIM);
  const float4* r4 = (const float4*)red;
  out4[threadIdx.x] = r4[threadIdx.x];
}

// One wave per batch element: acc = q0*e0 + q1*mono1 + q2*mono2 (each mono =
// sum of 4 partials; global /sum|q| scale cancels under L2 normalization),
// normalize, apply ff PQC, measure X/Y/Z per wire.
__global__ __launch_bounds__(256) void final_kernel(
    const float2* __restrict__ part1, const float2* __restrict__ part2,
    const float* __restrict__ qsvt, const float2* __restrict__ ffcs,
    float* __restrict__ out) {
  int b = (blockIdx.x * blockDim.x + threadIdx.x) >> 6;
  int lane = threadIdx.x & 63;
  float q0 = qsvt[0], q1 = qsvt[1], q2 = qsvt[2];

  float ar[16], ai[16];
  const float2* p1 = part1 + (size_t)b * DIM;
  const float2* p2 = part2 + (size_t)b * DIM;
#pragma unroll
  for (int r = 0; r < 16; ++r) {
    int n = r * 64 + lane;
    float m1r = 0.f, m1i = 0.f, m2r = 0.f, m2i = 0.f;
#pragma unroll
    for (int q = 0; q < 4; ++q) {
      float2 v1 = p1[n + q * PSTRIDE];
      float2 v2 = p2[n + q * PSTRIDE];
      m1r += v1.x; m1i += v1.y;
      m2r += v2.x; m2i += v2.y;
    }
    ar[r] = q1 * m1r + q2 * m2r;
    ai[r] = q1 * m1i + q2 * m2i;
  }
  if (lane == 0) ar[0] += q0;

  float nn = 0.f;
#pragma unroll
  for (int r = 0; r < 16; ++r) nn += ar[r] * ar[r] + ai[r] * ai[r];
#pragma unroll
  for (int o = 1; o < 64; o <<= 1) nn += __shfl_xor(nn, o);
  float inv = 1.f / sqrtf(nn);
#pragma unroll
  for (int r = 0; r < 16; ++r) { ar[r] *= inv; ai[r] *= inv; }

  apply_pqc(ar, ai, ffcs, lane);

#pragma unroll
  for (int w = 0; w < NQ; ++w) {
    const int p = 9 - w;
    float xr = 0.f, xi = 0.f, zz = 0.f;
    if (p >= 6) {
      const int m = 1 << (p - 6);
#pragma unroll
      for (int r = 0; r < 16; ++r) {
        float mag = ar[r] * ar[r] + ai[r] * ai[r];
        zz += (r & m) ? -mag : mag;
        if (!(r & m)) {
          int r1 = r | m;
          xr += ar[r] * ar[r1] + ai[r] * ai[r1];
          xi += ar[r] * ai[r1] - ai[r] * ar[r1];
        }
      }
    } else {
      const int lm = 1 << p;
      bool lo = !(lane & lm);
#pragma unroll
      for (int r = 0; r < 16; ++r) {
        float mag = ar[r] * ar[r] + ai[r] * ai[r];
        zz += lo ? mag : -mag;
        float pr = __shfl_xor(ar[r], lm);
        float pi = __shfl_xor(ai[r], lm);
        if (lo) {
          xr += ar[r] * pr + ai[r] * pi;
          xi += ar[r] * pi - ai[r] * pr;
        }
      }
    }
#pragma unroll
    for (int o = 1; o < 64; o <<= 1) {
      xr += __shfl_xor(xr, o);
      xi += __shfl_xor(xi, o);
      zz += __shfl_xor(zz, o);
    }
    if (lane == 0) {
      out[b * 30 + w]      = 2.f * xr;
      out[b * 30 + 10 + w] = 2.f * xi;
      out[b * 30 + 20 + w] = zz;
    }
  }
}

// ------------------------- launch ------------------------------------------

extern "C" void kernel_launch(void* const* d_in, const int* in_sizes, int n_in,
                              void* d_out, int out_size, void* d_ws, size_t ws_size,
                              hipStream_t stream) {
  const float* emb    = (const float*)d_in[0];
  const float* W      = (const float*)d_in[1];
  const float* bias   = (const float*)d_in[2];
  const float* lcu_re = (const float*)d_in[3];
  const float* lcu_im = (const float*)d_in[4];
  const float* qsvt   = (const float*)d_in[5];
  const float* ffp    = (const float*)d_in[6];
  float* out = (float*)d_out;

  char* ws = (char*)d_ws;
  // layout: cs[4096][40] f2 | ffcs[40] f2 | lcu[32] f2 | pad |
  //         part1[4][128][1024] f2 (4 MB) | part2[4][128][1024] f2 (4 MB)
  float2* cs    = (float2*)ws;                               // 1,310,720 B
  float2* ffcs  = (float2*)(ws + 1310720);                   //       320 B
  float2* lcu   = (float2*)(ws + 1311040);                   //       256 B
  float2* part1 = (float2*)(ws + 1311744);                   // 4,194,304 B (256B-aligned)
  float2* part2 = (float2*)(ws + 1311744 + 4194304);         // 4,194,304 B

  params_kernel<<<NROWS + 1, 320, 0, stream>>>(emb, W, bias, lcu_re, lcu_im, ffp,
                                               cs, ffcs, lcu);
  pqc_step<true><<<512, 512, 0, stream>>>(cs, lcu, nullptr, part1);
  pqc_step<false><<<512, 512, 0, stream>>>(cs, lcu, part1, part2);
  final_kernel<<<BATCH / 4, 256, 0, stream>>>(part1, part2, qsvt, ffcs, out);
}

// Round 3
// 212.552 us; speedup vs baseline: 1.5831x; 1.5831x over previous
//
#include <hip/hip_runtime.h>
#include <hip/hip_bf16.h>

// ---------------------------------------------------------------------------
// QuixerCore: 10-qubit QSVT/LCU quantum circuit simulator.
// R3: all gates act on REGISTER bits; lane<->reg bit layout is changed by
// LDS remaps (8 per PQC). No cross-lane shuffles in the hot path.
// Canonical layout: n = r*64+lane, wire w at bit 9-w (reg bits 6-9 = wires 3..0).
// Phase ledger (verified by permutation composition):
//  P0: RY w0..3 @9,8,7,6            | remap<5,4,3,2>
//  P1: RY w4..7 @6,7,8,9            | remap<1,0,2,3>
//  P2: RY w8@6,w9@7; CRX k10(c7,t8) k11(c6,t7) k12(c3,t6)   | remap<1,0,2,3>
//  P3: CRX k13(c8,t9) k14(c7,t8) k15(c6,t7) k16(c5,t6)      | remap<2,3,4,5>
//  P4: CRX k17(c8,t9) k18(c7,t8) k19(c6,t7); RY k20..23 @6,7,8,9 | remap<2,3,4,5>
//  P5: RY k24..27 @6,7,8,9          | remap<1,0,2,3>
//  P6: RY k28@6,k29@7; CRX k30(c7,t6) k31(c8,t7) k32(c9,t8) k33(c4,t9) | remap<4,5,1,0>
//  P7: CRX k34(c7,t6) k35(c8,t7) k36(c9,t8) k37(c2,t9)      | remap<2,3,4,5>
//  P8: CRX k38(c7,t6) k39(c8,t7)
// Final layout P8: wire->bit: w0=1, w1=0, w>=2: bit w.
// ---------------------------------------------------------------------------

#define NQ   10
#define NT   32
#define DM   512
#define BATCH 128
#define NPQC 40
#define DIM  1024
#define NROWS (BATCH * NT)    // 4096
#define PSTRIDE (BATCH * DIM) // elements per partial slice (float2)

// ------------------------- gate primitives ---------------------------------
// B = bit position of target in CURRENT layout (>=6 -> register bit).

template<int B>
__device__ __forceinline__ void g_ry(float (&ar)[16], float (&ai)[16], int lane,
                                     float c, float s) {
  static_assert(B >= 6, "RY targets must be register bits");
  constexpr int m = 1 << (B - 6);
#pragma unroll
  for (int r = 0; r < 16; ++r) {
    if (!(r & m)) {
      int r1 = r | m;
      float a0r = ar[r], a0i = ai[r], a1r = ar[r1], a1i = ai[r1];
      ar[r]  = c * a0r - s * a1r;  ai[r]  = c * a0i - s * a1i;
      ar[r1] = s * a0r + c * a1r;  ai[r1] = s * a0i + c * a1i;
    }
  }
}

// CRX: control bit BC (reg: compile-time skip; lane: predication), target BT (reg).
template<int BC, int BT>
__device__ __forceinline__ void g_crx(float (&ar)[16], float (&ai)[16], int lane,
                                      float c, float s) {
  static_assert(BT >= 6, "CRX targets must be register bits");
  constexpr int m = 1 << (BT - 6);
  bool lane_ok = (BC >= 6) || ((lane >> BC) & 1);
#pragma unroll
  for (int r = 0; r < 16; ++r) {
    if (!(r & m)) {
      if constexpr (BC >= 6) { if (!((r >> (BC - 6)) & 1)) continue; }
      int r1 = r | m;
      float a0r = ar[r], a0i = ai[r], a1r = ar[r1], a1i = ai[r1];
      float n0r = c * a0r + s * a1i, n0i = c * a0i - s * a1r;
      float n1r = c * a1r + s * a0i, n1i = c * a1i - s * a0r;
      if (lane_ok) { ar[r] = n0r; ai[r] = n0i; ar[r1] = n1r; ai[r1] = n1i; }
    }
  }
}

// ------------------------- layout remap ------------------------------------
// Swap reg bit (6+j) with lane bit Lj, j=0..3. Per-wave LDS slab (1024 f2).
// Bank swizzle: fold reg-origin bits into bank positions (XOR) -> conflict-free.
template<int L0, int L1, int L2, int L3>
__device__ __forceinline__ void remap(float (&ar)[16], float (&ai)[16],
                                      float2* __restrict__ slab, int lane) {
  constexpr int LM = (1 << L0) | (1 << L1) | (1 << L2) | (1 << L3);
#pragma unroll
  for (int r = 0; r < 16; ++r) {
    int f = 0;
    if (L0 < 4 && (r & 1)) f |= 1 << L0;
    if (L1 < 4 && (r & 2)) f |= 1 << L1;
    if (L2 < 4 && (r & 4)) f |= 1 << L2;
    if (L3 < 4 && (r & 8)) f |= 1 << L3;
    slab[r * 64 + (lane ^ f)] = make_float2(ar[r], ai[r]);
  }
  asm volatile("s_waitcnt lgkmcnt(0)" ::: "memory");
  int la = lane & ~LM & 63;
  la |= ((lane >> L0) & 1) << 6;
  la |= ((lane >> L1) & 1) << 7;
  la |= ((lane >> L2) & 1) << 8;
  la |= ((lane >> L3) & 1) << 9;
  if (L0 < 4) la |= ((lane >> L0) & 1) << L0;
  if (L1 < 4) la |= ((lane >> L1) & 1) << L1;
  if (L2 < 4) la |= ((lane >> L2) & 1) << L2;
  if (L3 < 4) la |= ((lane >> L3) & 1) << L3;
#pragma unroll
  for (int r = 0; r < 16; ++r) {
    int rc = ((r & 1) ? (1 << L0) : 0) | ((r & 2) ? (1 << L1) : 0)
           | ((r & 4) ? (1 << L2) : 0) | ((r & 8) ? (1 << L3) : 0);
    float2 v = slab[la ^ rc];
    ar[r] = v.x; ai[r] = v.y;
  }
}

// ------------------------- phased PQC --------------------------------------
__device__ __forceinline__ void apply_pqc_phased(float (&ar)[16], float (&ai)[16],
    const float2* __restrict__ cs, float2* __restrict__ slab, int lane) {
  float2 t;
#define RYB(k, B)      t = cs[k]; g_ry<B>(ar, ai, lane, t.x, t.y);
#define CXB(k, BC, BT) t = cs[k]; g_crx<BC, BT>(ar, ai, lane, t.x, t.y);
  RYB(0,9) RYB(1,8) RYB(2,7) RYB(3,6)
  remap<5,4,3,2>(ar, ai, slab, lane);
  RYB(4,6) RYB(5,7) RYB(6,8) RYB(7,9)
  remap<1,0,2,3>(ar, ai, slab, lane);
  RYB(8,6) RYB(9,7)
  CXB(10,7,8) CXB(11,6,7) CXB(12,3,6)
  remap<1,0,2,3>(ar, ai, slab, lane);
  CXB(13,8,9) CXB(14,7,8) CXB(15,6,7) CXB(16,5,6)
  remap<2,3,4,5>(ar, ai, slab, lane);
  CXB(17,8,9) CXB(18,7,8) CXB(19,6,7)
  RYB(20,6) RYB(21,7) RYB(22,8) RYB(23,9)
  remap<2,3,4,5>(ar, ai, slab, lane);
  RYB(24,6) RYB(25,7) RYB(26,8) RYB(27,9)
  remap<1,0,2,3>(ar, ai, slab, lane);
  RYB(28,6) RYB(29,7)
  CXB(30,7,6) CXB(31,8,7) CXB(32,9,8) CXB(33,4,9)
  remap<4,5,1,0>(ar, ai, slab, lane);
  CXB(34,7,6) CXB(35,8,7) CXB(36,9,8) CXB(37,2,9)
  remap<2,3,4,5>(ar, ai, slab, lane);
  CXB(38,7,6) CXB(39,8,7)
#undef RYB
#undef CXB
}

// P8 -> canonical index pieces for the output conversion.
// lane part: canonical bits 9..4 = lane bits 1,0,2,3,4,5 ; reg part = rev4(r).
__device__ __forceinline__ int p8_lane_canon(int lane) {
  return (((lane >> 1) & 1) << 9) | ((lane & 1) << 8) | (((lane >> 2) & 1) << 7)
       | (((lane >> 3) & 1) << 6) | (((lane >> 4) & 1) << 5) | (((lane >> 5) & 1) << 4);
}

// ------------------------- kernels -----------------------------------------

__global__ __launch_bounds__(320) void params_kernel(
    const float* __restrict__ emb, const float* __restrict__ W,
    const float* __restrict__ bias,
    const float* __restrict__ lcu_re, const float* __restrict__ lcu_im,
    const float* __restrict__ ffp,
    float2* __restrict__ cs, float2* __restrict__ ffcs, float2* __restrict__ lcu) {
  int row = blockIdx.x;
  int t = threadIdx.x;
  if (row == NROWS) {
    if (t < NPQC) {
      float h = 0.5f * ffp[t];
      ffcs[t] = make_float2(cosf(h), sinf(h));
    }
    if (t == 64) {
      float ssum = 0.f;
      for (int i = 0; i < NT; ++i) {
        float re = lcu_re[i], im = lcu_im[i];
        ssum += sqrtf(re * re + im * im);
      }
      float inv = 1.f / ssum;
      for (int i = 0; i < NT; ++i)
        lcu[i] = make_float2(lcu_re[i] * inv, lcu_im[i] * inv);
    }
    return;
  }
  __shared__ float partials[NPQC][8];
  int k = t >> 3, part = t & 7;
  const float4* e4 = (const float4*)(emb + (size_t)row * DM + part * 64);
  const float4* w4 = (const float4*)(W + (size_t)k * DM + part * 64);
  float acc = 0.f;
#pragma unroll
  for (int i = 0; i < 16; ++i) {
    float4 a = e4[i], b = w4[i];
    acc += a.x * b.x + a.y * b.y + a.z * b.z + a.w * b.w;
  }
  partials[k][part] = acc;
  __syncthreads();
  if (t < NPQC) {
    float v = bias[t];
#pragma unroll
    for (int p = 0; p < 8; ++p) v += partials[t][p];
    float h = 0.5f * v;
    cs[(size_t)row * NPQC + t] = make_float2(cosf(h), sinf(h));
  }
}

// One QSVT step. grid = 512 (b = blk>>2, quarter qq = blk&3), block = 512 = 8 waves,
// wave wv -> token l = qq*8+wv. Per-wave slab remap PQC, then weighted state ->
// own slab in canonical(phys) layout, block-reduce 8 slabs -> partial slice.
template<bool FIRST>
__global__ __launch_bounds__(512) void pqc_step(
    const float2* __restrict__ cs, const float2* __restrict__ lcu,
    const float2* __restrict__ src, float2* __restrict__ dst) {
  __shared__ float2 slabs[8][1024];   // 64 KB
  int lane = threadIdx.x & 63;
  int wvu = __builtin_amdgcn_readfirstlane(threadIdx.x >> 6);
  int blk = blockIdx.x;
  int b = blk >> 2, qq = blk & 3;
  int l = qq * 8 + wvu;
  const float2* csrow = cs + (size_t)(b * NT + l) * NPQC;
  float2* slab = slabs[wvu];

  float ar[16], ai[16];
  if constexpr (FIRST) {
#pragma unroll
    for (int r = 0; r < 16; ++r) { ar[r] = 0.f; ai[r] = 0.f; }
    if (lane == 0) ar[0] = 1.f;   // |0...0>
  } else {
    const float2* s = src + (size_t)b * DIM;
#pragma unroll
    for (int r = 0; r < 16; ++r) {
      int n = r * 64 + lane;
      float2 v0 = s[n];
      float2 v1 = s[n + PSTRIDE];
      float2 v2 = s[n + 2 * PSTRIDE];
      float2 v3 = s[n + 3 * PSTRIDE];
      ar[r] = v0.x + v1.x + v2.x + v3.x;
      ai[r] = v0.y + v1.y + v2.y + v3.y;
    }
  }

  apply_pqc_phased(ar, ai, csrow, slab, lane);

  // weighted write into own slab at canonical swizzled index
  float2 w = lcu[l];
  int pl = p8_lane_canon(lane);
  pl ^= (pl >> 5);
#pragma unroll
  for (int r = 0; r < 16; ++r) {
    int rc = ((r & 1) << 3) | ((r & 2) << 1) | ((r & 4) >> 1) | ((r & 8) >> 3); // rev4
    float cr = w.x * ar[r] - w.y * ai[r];
    float ci = w.x * ai[r] + w.y * ar[r];
    slab[pl ^ rc] = make_float2(cr, ci);
  }
  __syncthreads();

  // reduce 8 slabs -> global partial slice (canonical layout)
  float2* dst_b = dst + (size_t)(qq * BATCH + b) * DIM;
#pragma unroll
  for (int i = 0; i < 2; ++i) {
    int n = threadIdx.x + i * 512;
    int ph = n ^ (n >> 5);
    float sr = 0.f, si = 0.f;
#pragma unroll
    for (int s = 0; s < 8; ++s) { float2 v = slabs[s][ph]; sr += v.x; si += v.y; }
    dst_b[n] = make_float2(sr, si);
  }
}

// One wave per batch element: acc = q0*e0 + q1*mono1 + q2*mono2, normalize,
// apply ff PQC (phased), measure X/Y/Z per wire in P8 layout.
__global__ __launch_bounds__(256) void final_kernel(
    const float2* __restrict__ part1, const float2* __restrict__ part2,
    const float* __restrict__ qsvt, const float2* __restrict__ ffcs,
    float* __restrict__ out) {
  __shared__ float2 slabs[4][1024];   // 32 KB
  int lane = threadIdx.x & 63;
  int wvu = __builtin_amdgcn_readfirstlane(threadIdx.x >> 6);
  int b = blockIdx.x * 4 + wvu;
  float q0 = qsvt[0], q1 = qsvt[1], q2 = qsvt[2];

  float ar[16], ai[16];
  const float2* p1 = part1 + (size_t)b * DIM;
  const float2* p2 = part2 + (size_t)b * DIM;
#pragma unroll
  for (int r = 0; r < 16; ++r) {
    int n = r * 64 + lane;
    float m1r = 0.f, m1i = 0.f, m2r = 0.f, m2i = 0.f;
#pragma unroll
    for (int q = 0; q < 4; ++q) {
      float2 v1 = p1[n + q * PSTRIDE];
      float2 v2 = p2[n + q * PSTRIDE];
      m1r += v1.x; m1i += v1.y;
      m2r += v2.x; m2i += v2.y;
    }
    ar[r] = q1 * m1r + q2 * m2r;
    ai[r] = q1 * m1i + q2 * m2i;
  }
  if (lane == 0) ar[0] += q0;

  float nn = 0.f;
#pragma unroll
  for (int r = 0; r < 16; ++r) nn += ar[r] * ar[r] + ai[r] * ai[r];
#pragma unroll
  for (int o = 1; o < 64; o <<= 1) nn += __shfl_xor(nn, o);
  float inv = 1.f / sqrtf(nn);
#pragma unroll
  for (int r = 0; r < 16; ++r) { ar[r] *= inv; ai[r] *= inv; }

  apply_pqc_phased(ar, ai, ffcs, slabs[wvu], lane);

  // measurement in P8 layout: wire w bit position BPOS[w]
  constexpr int BPOS[10] = {1, 0, 2, 3, 4, 5, 6, 7, 8, 9};
#pragma unroll
  for (int w = 0; w < NQ; ++w) {
    const int p = BPOS[w];
    float xr = 0.f, xi = 0.f, zz = 0.f;
    if (p >= 6) {
      const int m = 1 << (p - 6);
#pragma unroll
      for (int r = 0; r < 16; ++r) {
        float mag = ar[r] * ar[r] + ai[r] * ai[r];
        zz += (r & m) ? -mag : mag;
        if (!(r & m)) {
          int r1 = r | m;
          xr += ar[r] * ar[r1] + ai[r] * ai[r1];
          xi += ar[r] * ai[r1] - ai[r] * ar[r1];
        }
      }
    } else {
      const int lm = 1 << p;
      bool lo = !(lane & lm);
#pragma unroll
      for (int r = 0; r < 16; ++r) {
        float mag = ar[r] * ar[r] + ai[r] * ai[r];
        zz += lo ? mag : -mag;
        float pr = __shfl_xor(ar[r], lm);
        float pi = __shfl_xor(ai[r], lm);
        if (lo) {
          xr += ar[r] * pr + ai[r] * pi;
          xi += ar[r] * pi - ai[r] * pr;
        }
      }
    }
#pragma unroll
    for (int o = 1; o < 64; o <<= 1) {
      xr += __shfl_xor(xr, o);
      xi += __shfl_xor(xi, o);
      zz += __shfl_xor(zz, o);
    }
    if (lane == 0) {
      out[b * 30 + w]      = 2.f * xr;
      out[b * 30 + 10 + w] = 2.f * xi;
      out[b * 30 + 20 + w] = zz;
    }
  }
}

// ------------------------- launch ------------------------------------------

extern "C" void kernel_launch(void* const* d_in, const int* in_sizes, int n_in,
                              void* d_out, int out_size, void* d_ws, size_t ws_size,
                              hipStream_t stream) {
  const float* emb    = (const float*)d_in[0];
  const float* W      = (const float*)d_in[1];
  const float* bias   = (const float*)d_in[2];
  const float* lcu_re = (const float*)d_in[3];
  const float* lcu_im = (const float*)d_in[4];
  const float* qsvt   = (const float*)d_in[5];
  const float* ffp    = (const float*)d_in[6];
  float* out = (float*)d_out;

  char* ws = (char*)d_ws;
  // layout: cs[4096][40] f2 | ffcs[40] f2 | lcu[32] f2 | pad |
  //         part1[4][128][1024] f2 (4 MB) | part2[4][128][1024] f2 (4 MB)
  float2* cs    = (float2*)ws;                               // 1,310,720 B
  float2* ffcs  = (float2*)(ws + 1310720);                   //       320 B
  float2* lcu   = (float2*)(ws + 1311040);                   //       256 B
  float2* part1 = (float2*)(ws + 1311744);                   // 4,194,304 B
  float2* part2 = (float2*)(ws + 1311744 + 4194304);         // 4,194,304 B

  params_kernel<<<NROWS + 1, 320, 0, stream>>>(emb, W, bias, lcu_re, lcu_im, ffp,
                                               cs, ffcs, lcu);
  pqc_step<true><<<512, 512, 0, stream>>>(cs, lcu, nullptr, part1);
  pqc_step<false><<<512, 512, 0, stream>>>(cs, lcu, part1, part2);
  final_kernel<<<BATCH / 4, 256, 0, stream>>>(part1, part2, qsvt, ffcs, out);
}

// Round 4
// 157.548 us; speedup vs baseline: 2.1358x; 1.3491x over previous
//
#include <hip/hip_runtime.h>
#include <hip/hip_bf16.h>

// ---------------------------------------------------------------------------
// QuixerCore: 10-qubit QSVT/LCU quantum circuit simulator.
// R3: phased-LDS PQC (gates only on register bits; 8 LDS layout remaps).
// R4: params GEMM rewritten as register-tiled (block = 16 rows x 40 cols,
//     K split over 4 waves, 2x5 accumulator tile per lane, A staged in LDS).
// Canonical layout: n = r*64+lane, wire w at bit 9-w (reg bits 6-9 = wires 3..0).
// ---------------------------------------------------------------------------

#define NQ   10
#define NT   32
#define DM   512
#define BATCH 128
#define NPQC 40
#define DIM  1024
#define NROWS (BATCH * NT)    // 4096
#define PSTRIDE (BATCH * DIM) // elements per partial slice (float2)

// ------------------------- gate primitives ---------------------------------

template<int B>
__device__ __forceinline__ void g_ry(float (&ar)[16], float (&ai)[16], int lane,
                                     float c, float s) {
  static_assert(B >= 6, "RY targets must be register bits");
  constexpr int m = 1 << (B - 6);
#pragma unroll
  for (int r = 0; r < 16; ++r) {
    if (!(r & m)) {
      int r1 = r | m;
      float a0r = ar[r], a0i = ai[r], a1r = ar[r1], a1i = ai[r1];
      ar[r]  = c * a0r - s * a1r;  ai[r]  = c * a0i - s * a1i;
      ar[r1] = s * a0r + c * a1r;  ai[r1] = s * a0i + c * a1i;
    }
  }
}

template<int BC, int BT>
__device__ __forceinline__ void g_crx(float (&ar)[16], float (&ai)[16], int lane,
                                      float c, float s) {
  static_assert(BT >= 6, "CRX targets must be register bits");
  constexpr int m = 1 << (BT - 6);
  bool lane_ok = (BC >= 6) || ((lane >> BC) & 1);
#pragma unroll
  for (int r = 0; r < 16; ++r) {
    if (!(r & m)) {
      if constexpr (BC >= 6) { if (!((r >> (BC - 6)) & 1)) continue; }
      int r1 = r | m;
      float a0r = ar[r], a0i = ai[r], a1r = ar[r1], a1i = ai[r1];
      float n0r = c * a0r + s * a1i, n0i = c * a0i - s * a1r;
      float n1r = c * a1r + s * a0i, n1i = c * a1i - s * a0r;
      if (lane_ok) { ar[r] = n0r; ai[r] = n0i; ar[r1] = n1r; ai[r1] = n1i; }
    }
  }
}

// ------------------------- layout remap ------------------------------------
template<int L0, int L1, int L2, int L3>
__device__ __forceinline__ void remap(float (&ar)[16], float (&ai)[16],
                                      float2* __restrict__ slab, int lane) {
  constexpr int LM = (1 << L0) | (1 << L1) | (1 << L2) | (1 << L3);
#pragma unroll
  for (int r = 0; r < 16; ++r) {
    int f = 0;
    if (L0 < 4 && (r & 1)) f |= 1 << L0;
    if (L1 < 4 && (r & 2)) f |= 1 << L1;
    if (L2 < 4 && (r & 4)) f |= 1 << L2;
    if (L3 < 4 && (r & 8)) f |= 1 << L3;
    slab[r * 64 + (lane ^ f)] = make_float2(ar[r], ai[r]);
  }
  asm volatile("s_waitcnt lgkmcnt(0)" ::: "memory");
  int la = lane & ~LM & 63;
  la |= ((lane >> L0) & 1) << 6;
  la |= ((lane >> L1) & 1) << 7;
  la |= ((lane >> L2) & 1) << 8;
  la |= ((lane >> L3) & 1) << 9;
  if (L0 < 4) la |= ((lane >> L0) & 1) << L0;
  if (L1 < 4) la |= ((lane >> L1) & 1) << L1;
  if (L2 < 4) la |= ((lane >> L2) & 1) << L2;
  if (L3 < 4) la |= ((lane >> L3) & 1) << L3;
#pragma unroll
  for (int r = 0; r < 16; ++r) {
    int rc = ((r & 1) ? (1 << L0) : 0) | ((r & 2) ? (1 << L1) : 0)
           | ((r & 4) ? (1 << L2) : 0) | ((r & 8) ? (1 << L3) : 0);
    float2 v = slab[la ^ rc];
    ar[r] = v.x; ai[r] = v.y;
  }
}

// ------------------------- phased PQC --------------------------------------
__device__ __forceinline__ void apply_pqc_phased(float (&ar)[16], float (&ai)[16],
    const float2* __restrict__ cs, float2* __restrict__ slab, int lane) {
  float2 t;
#define RYB(k, B)      t = cs[k]; g_ry<B>(ar, ai, lane, t.x, t.y);
#define CXB(k, BC, BT) t = cs[k]; g_crx<BC, BT>(ar, ai, lane, t.x, t.y);
  RYB(0,9) RYB(1,8) RYB(2,7) RYB(3,6)
  remap<5,4,3,2>(ar, ai, slab, lane);
  RYB(4,6) RYB(5,7) RYB(6,8) RYB(7,9)
  remap<1,0,2,3>(ar, ai, slab, lane);
  RYB(8,6) RYB(9,7)
  CXB(10,7,8) CXB(11,6,7) CXB(12,3,6)
  remap<1,0,2,3>(ar, ai, slab, lane);
  CXB(13,8,9) CXB(14,7,8) CXB(15,6,7) CXB(16,5,6)
  remap<2,3,4,5>(ar, ai, slab, lane);
  CXB(17,8,9) CXB(18,7,8) CXB(19,6,7)
  RYB(20,6) RYB(21,7) RYB(22,8) RYB(23,9)
  remap<2,3,4,5>(ar, ai, slab, lane);
  RYB(24,6) RYB(25,7) RYB(26,8) RYB(27,9)
  remap<1,0,2,3>(ar, ai, slab, lane);
  RYB(28,6) RYB(29,7)
  CXB(30,7,6) CXB(31,8,7) CXB(32,9,8) CXB(33,4,9)
  remap<4,5,1,0>(ar, ai, slab, lane);
  CXB(34,7,6) CXB(35,8,7) CXB(36,9,8) CXB(37,2,9)
  remap<2,3,4,5>(ar, ai, slab, lane);
  CXB(38,7,6) CXB(39,8,7)
#undef RYB
#undef CXB
}

__device__ __forceinline__ int p8_lane_canon(int lane) {
  return (((lane >> 1) & 1) << 9) | ((lane & 1) << 8) | (((lane >> 2) & 1) << 7)
       | (((lane >> 3) & 1) << 6) | (((lane >> 4) & 1) << 5) | (((lane >> 5) & 1) << 4);
}

// ------------------------- params: register-tiled GEMM ----------------------
// grid = 257 blocks x 256 thr. Blocks 0..255: 16 rows x 40 cols, K split over
// 4 waves (128 each). Lane tile: 2 rows x 5 cols. A staged in LDS (stride 516,
// bank-checked); B (W, 80 KB) read from global (L1/L2-resident). K-partials
// reduced through LDS; bias + cos/sin fused. Block 256: ffcs + lcu.
__global__ __launch_bounds__(256) void params_kernel(
    const float* __restrict__ emb, const float* __restrict__ W,
    const float* __restrict__ bias,
    const float* __restrict__ lcu_re, const float* __restrict__ lcu_im,
    const float* __restrict__ ffp,
    float2* __restrict__ cs, float2* __restrict__ ffcs, float2* __restrict__ lcu) {
  int blk = blockIdx.x;
  int tid = threadIdx.x;
  if (blk == 256) {
    if (tid < NPQC) {
      float h = 0.5f * ffp[tid];
      ffcs[tid] = make_float2(cosf(h), sinf(h));
    }
    if (tid == 64) {
      float ssum = 0.f;
      for (int i = 0; i < NT; ++i) {
        float re = lcu_re[i], im = lcu_im[i];
        ssum += sqrtf(re * re + im * im);
      }
      float inv = 1.f / ssum;
      for (int i = 0; i < NT; ++i)
        lcu[i] = make_float2(lcu_re[i] * inv, lcu_im[i] * inv);
    }
    return;
  }

  __shared__ float Asl[16 * 516];   // 33 KB; also reused as reduction buffer
  int row0 = blk * 16;

  // stage A: 16 rows x 512 floats = 2048 float4, 8 per thread, coalesced
  const float4* eg = (const float4*)(emb + (size_t)row0 * DM);
#pragma unroll
  for (int i = 0; i < 8; ++i) {
    int e = tid + i * 256;
    int r = e >> 7, k4 = e & 127;
    float4 v = eg[e];                       // e == r*128 + k4
    *(float4*)&Asl[r * 516 + k4 * 4] = v;
  }
  __syncthreads();

  int kq = tid >> 6;        // wave id: K-range [kq*128, kq*128+128)
  int lane = tid & 63;
  int rg = lane >> 3;       // rows 2rg, 2rg+1
  int cg = lane & 7;        // cols 5cg .. 5cg+4

  const float* Ar0 = &Asl[(2 * rg) * 516 + kq * 128];
  const float* Ar1 = Ar0 + 516;
  const float* Bg  = W + (size_t)(5 * cg) * DM + kq * 128;

  float acc[2][5] = {};
#pragma unroll 4
  for (int k = 0; k < 128; k += 4) {
    float4 a0 = *(const float4*)(Ar0 + k);
    float4 a1 = *(const float4*)(Ar1 + k);
#pragma unroll
    for (int j = 0; j < 5; ++j) {
      float4 b = *(const float4*)(Bg + j * DM + k);
      acc[0][j] += a0.x * b.x + a0.y * b.y + a0.z * b.z + a0.w * b.w;
      acc[1][j] += a1.x * b.x + a1.y * b.y + a1.z * b.z + a1.w * b.w;
    }
  }

  __syncthreads();   // all waves done reading Asl before we overwrite it
  float* red = Asl;  // 4 slices of 640, stride 644
#pragma unroll
  for (int i = 0; i < 2; ++i)
#pragma unroll
    for (int j = 0; j < 5; ++j)
      red[kq * 644 + (2 * rg + i) * 40 + 5 * cg + j] = acc[i][j];
  __syncthreads();

  for (int o = tid; o < 640; o += 256) {
    float v = bias[o % 40] + red[o] + red[644 + o] + red[1288 + o] + red[1932 + o];
    float h = 0.5f * v;
    cs[(size_t)blk * 640 + o] = make_float2(cosf(h), sinf(h));
  }
}

// ------------------------- QSVT step ---------------------------------------
template<bool FIRST>
__global__ __launch_bounds__(512) void pqc_step(
    const float2* __restrict__ cs, const float2* __restrict__ lcu,
    const float2* __restrict__ src, float2* __restrict__ dst) {
  __shared__ float2 slabs[8][1024];   // 64 KB
  int lane = threadIdx.x & 63;
  int wvu = __builtin_amdgcn_readfirstlane(threadIdx.x >> 6);
  int blk = blockIdx.x;
  int b = blk >> 2, qq = blk & 3;
  int l = qq * 8 + wvu;
  const float2* csrow = cs + (size_t)(b * NT + l) * NPQC;
  float2* slab = slabs[wvu];

  float ar[16], ai[16];
  if constexpr (FIRST) {
#pragma unroll
    for (int r = 0; r < 16; ++r) { ar[r] = 0.f; ai[r] = 0.f; }
    if (lane == 0) ar[0] = 1.f;   // |0...0>
  } else {
    const float2* s = src + (size_t)b * DIM;
#pragma unroll
    for (int r = 0; r < 16; ++r) {
      int n = r * 64 + lane;
      float2 v0 = s[n];
      float2 v1 = s[n + PSTRIDE];
      float2 v2 = s[n + 2 * PSTRIDE];
      float2 v3 = s[n + 3 * PSTRIDE];
      ar[r] = v0.x + v1.x + v2.x + v3.x;
      ai[r] = v0.y + v1.y + v2.y + v3.y;
    }
  }

  apply_pqc_phased(ar, ai, csrow, slab, lane);

  // weighted write into own slab at canonical swizzled index
  float2 w = lcu[l];
  int pl = p8_lane_canon(lane);
  pl ^= (pl >> 5);
#pragma unroll
  for (int r = 0; r < 16; ++r) {
    int rc = ((r & 1) << 3) | ((r & 2) << 1) | ((r & 4) >> 1) | ((r & 8) >> 3); // rev4
    float cr = w.x * ar[r] - w.y * ai[r];
    float ci = w.x * ai[r] + w.y * ar[r];
    slab[pl ^ rc] = make_float2(cr, ci);
  }
  __syncthreads();

  // reduce 8 slabs -> global partial slice (canonical layout)
  float2* dst_b = dst + (size_t)(qq * BATCH + b) * DIM;
#pragma unroll
  for (int i = 0; i < 2; ++i) {
    int n = threadIdx.x + i * 512;
    int ph = n ^ (n >> 5);
    float sr = 0.f, si = 0.f;
#pragma unroll
    for (int s = 0; s < 8; ++s) { float2 v = slabs[s][ph]; sr += v.x; si += v.y; }
    dst_b[n] = make_float2(sr, si);
  }
}

// ------------------------- final -------------------------------------------
__global__ __launch_bounds__(256) void final_kernel(
    const float2* __restrict__ part1, const float2* __restrict__ part2,
    const float* __restrict__ qsvt, const float2* __restrict__ ffcs,
    float* __restrict__ out) {
  __shared__ float2 slabs[4][1024];   // 32 KB
  int lane = threadIdx.x & 63;
  int wvu = __builtin_amdgcn_readfirstlane(threadIdx.x >> 6);
  int b = blockIdx.x * 4 + wvu;
  float q0 = qsvt[0], q1 = qsvt[1], q2 = qsvt[2];

  float ar[16], ai[16];
  const float2* p1 = part1 + (size_t)b * DIM;
  const float2* p2 = part2 + (size_t)b * DIM;
#pragma unroll
  for (int r = 0; r < 16; ++r) {
    int n = r * 64 + lane;
    float m1r = 0.f, m1i = 0.f, m2r = 0.f, m2i = 0.f;
#pragma unroll
    for (int q = 0; q < 4; ++q) {
      float2 v1 = p1[n + q * PSTRIDE];
      float2 v2 = p2[n + q * PSTRIDE];
      m1r += v1.x; m1i += v1.y;
      m2r += v2.x; m2i += v2.y;
    }
    ar[r] = q1 * m1r + q2 * m2r;
    ai[r] = q1 * m1i + q2 * m2i;
  }
  if (lane == 0) ar[0] += q0;

  float nn = 0.f;
#pragma unroll
  for (int r = 0; r < 16; ++r) nn += ar[r] * ar[r] + ai[r] * ai[r];
#pragma unroll
  for (int o = 1; o < 64; o <<= 1) nn += __shfl_xor(nn, o);
  float inv = 1.f / sqrtf(nn);
#pragma unroll
  for (int r = 0; r < 16; ++r) { ar[r] *= inv; ai[r] *= inv; }

  apply_pqc_phased(ar, ai, ffcs, slabs[wvu], lane);

  constexpr int BPOS[10] = {1, 0, 2, 3, 4, 5, 6, 7, 8, 9};
#pragma unroll
  for (int w = 0; w < NQ; ++w) {
    const int p = BPOS[w];
    float xr = 0.f, xi = 0.f, zz = 0.f;
    if (p >= 6) {
      const int m = 1 << (p - 6);
#pragma unroll
      for (int r = 0; r < 16; ++r) {
        float mag = ar[r] * ar[r] + ai[r] * ai[r];
        zz += (r & m) ? -mag : mag;
        if (!(r & m)) {
          int r1 = r | m;
          xr += ar[r] * ar[r1] + ai[r] * ai[r1];
          xi += ar[r] * ai[r1] - ai[r] * ar[r1];
        }
      }
    } else {
      const int lm = 1 << p;
      bool lo = !(lane & lm);
#pragma unroll
      for (int r = 0; r < 16; ++r) {
        float mag = ar[r] * ar[r] + ai[r] * ai[r];
        zz += lo ? mag : -mag;
        float pr = __shfl_xor(ar[r], lm);
        float pi = __shfl_xor(ai[r], lm);
        if (lo) {
          xr += ar[r] * pr + ai[r] * pi;
          xi += ar[r] * pi - ai[r] * pr;
        }
      }
    }
#pragma unroll
    for (int o = 1; o < 64; o <<= 1) {
      xr += __shfl_xor(xr, o);
      xi += __shfl_xor(xi, o);
      zz += __shfl_xor(zz, o);
    }
    if (lane == 0) {
      out[b * 30 + w]      = 2.f * xr;
      out[b * 30 + 10 + w] = 2.f * xi;
      out[b * 30 + 20 + w] = zz;
    }
  }
}

// ------------------------- launch ------------------------------------------

extern "C" void kernel_launch(void* const* d_in, const int* in_sizes, int n_in,
                              void* d_out, int out_size, void* d_ws, size_t ws_size,
                              hipStream_t stream) {
  const float* emb    = (const float*)d_in[0];
  const float* W      = (const float*)d_in[1];
  const float* bias   = (const float*)d_in[2];
  const float* lcu_re = (const float*)d_in[3];
  const float* lcu_im = (const float*)d_in[4];
  const float* qsvt   = (const float*)d_in[5];
  const float* ffp    = (const float*)d_in[6];
  float* out = (float*)d_out;

  char* ws = (char*)d_ws;
  float2* cs    = (float2*)ws;                               // 1,310,720 B
  float2* ffcs  = (float2*)(ws + 1310720);                   //       320 B
  float2* lcu   = (float2*)(ws + 1311040);                   //       256 B
  float2* part1 = (float2*)(ws + 1311744);                   // 4,194,304 B
  float2* part2 = (float2*)(ws + 1311744 + 4194304);         // 4,194,304 B

  params_kernel<<<257, 256, 0, stream>>>(emb, W, bias, lcu_re, lcu_im, ffp,
                                         cs, ffcs, lcu);
  pqc_step<true><<<512, 512, 0, stream>>>(cs, lcu, nullptr, part1);
  pqc_step<false><<<512, 512, 0, stream>>>(cs, lcu, part1, part2);
  final_kernel<<<BATCH / 4, 256, 0, stream>>>(part1, part2, qsvt, ffcs, out);
}